// Round 12
// baseline (216.609 us; speedup 1.0000x reference)
//
#include <hip/hip_runtime.h>
#include <cstdint>
#include <cstddef>

static constexpr int Bz = 4, S = 2048, Dm = 1024, H = 16, DK = 64;
static constexpr int M = Bz * S;  // 8192

typedef __attribute__((ext_vector_type(8))) short bf16x8;
typedef __attribute__((ext_vector_type(4))) float f32x4;

__device__ __forceinline__ unsigned short f2b(float f) {
    unsigned u = __float_as_uint(f);
    return (unsigned short)((u + 0x7FFFu + ((u >> 16) & 1u)) >> 16);  // RNE
}

__device__ __forceinline__ unsigned cvtpk(float lo, float hi) {
    unsigned r;
    asm("v_cvt_pk_bf16_f32 %0, %1, %2" : "=v"(r) : "v"(lo), "v"(hi));
    return r;
}

// raw v_exp_f32 (exp2) — avoids OCML exp2f's range-check fixup code
__device__ __forceinline__ float fexp2(float x) {
#if __has_builtin(__builtin_amdgcn_exp2f)
    return __builtin_amdgcn_exp2f(x);
#else
    float r;
    asm("v_exp_f32 %0, %1" : "=v"(r) : "v"(x));
    return r;
#endif
}

__device__ __forceinline__ void gld_lds16(const void* g, void* l) {
    __builtin_amdgcn_global_load_lds(
        (const __attribute__((address_space(1))) unsigned int*)g,
        (__attribute__((address_space(3))) unsigned int*)l, 16, 0, 0);
}

// ---- K0a: x fp32 -> bf16, plus key-pad mask (any feature == 0) ----
__global__ __launch_bounds__(256) void k_convx(const float* __restrict__ x,
                                               unsigned short* __restrict__ xb,
                                               unsigned char* __restrict__ mask) {
    const int row = blockIdx.x;
    const int t = threadIdx.x;
    const float4 v = *(const float4*)(x + (size_t)row * Dm + t * 4);
    const bool z = (v.x == 0.f) | (v.y == 0.f) | (v.z == 0.f) | (v.w == 0.f);
    ushort4 o;
    o.x = f2b(v.x); o.y = f2b(v.y); o.z = f2b(v.z); o.w = f2b(v.w);
    *(ushort4*)(xb + (size_t)row * Dm + t * 4) = o;
    __shared__ int zf;
    if (t == 0) zf = 0;
    __syncthreads();
    if (z) zf = 1;
    __syncthreads();
    if (t == 0) mask[row] = (unsigned char)zf;
}

// ---- K0b: weights fp32 [K][N] -> bf16 transposed [N][K] ----
__global__ __launch_bounds__(256) void k_convw(const float* __restrict__ Wq, const float* __restrict__ Wk,
                                               const float* __restrict__ Wv, const float* __restrict__ Wo,
                                               unsigned short* __restrict__ Wt) {
    const float* W = (blockIdx.z == 0) ? Wq : (blockIdx.z == 1) ? Wk : (blockIdx.z == 2) ? Wv : Wo;
    unsigned short* o = Wt + (size_t)blockIdx.z * Dm * Dm;
    __shared__ float tile[32][33];
    const int k0 = blockIdx.x * 32, n0 = blockIdx.y * 32;
    const int tx = threadIdx.x, ty = threadIdx.y;
#pragma unroll
    for (int i = 0; i < 4; i++)
        tile[ty + 8 * i][tx] = W[(size_t)(k0 + ty + 8 * i) * Dm + n0 + tx];
    __syncthreads();
#pragma unroll
    for (int i = 0; i < 4; i++)
        o[(size_t)(n0 + ty + 8 * i) * Dm + k0 + tx] = f2b(tile[tx][ty + 8 * i]);
}

// ---- GEMM-0 (QKV): 8-phase-class schedule.  BM=256 BN=128 BK=64, 8 waves
//      (4M x 2N, 64x64/wave), LDS 96KB dbuf, XOR-swizzled (row&7 involution,
//      pre-swizzled gld_lds source + swizzled ds_read).  2 phases/K-tile:
//      {12 ds_read_b128 | stage burst (phase0) | barrier | lgkm(0) | 16 MFMA
//       (setprio) | barrier};  vmcnt(0)+barrier once per K-tile.
//      Grid 32x24 = 768 = exactly 3 rounds of 256 CUs.
//      Epilogue: Q pre-scaled by 1/sqrt(dk)*log2(e); V^T k'-permuted. ----
__global__ __launch_bounds__(512, 1) void k_g0(
    const unsigned short* __restrict__ A,
    const unsigned short* __restrict__ Bw,
    const float* __restrict__ bq, const float* __restrict__ bk, const float* __restrict__ bv,
    unsigned short* __restrict__ Qo, unsigned short* __restrict__ Ko,
    unsigned short* __restrict__ Vto)
{
    __shared__ unsigned short sA[2][256 * 64];   // 2 x 32KB
    __shared__ unsigned short sB[2][128 * 64];   // 2 x 16KB
    const int m0 = blockIdx.x * 256;
    const int n0 = blockIdx.y * 128;
    const int tid = threadIdx.x;
    const int lane = tid & 63;
    const int wid = tid >> 6;      // 8 waves
    const int wm = wid >> 1;       // 0..3 (M)
    const int wn = wid & 1;        // 0..1 (N)
    const int lr = lane & 15, lg = lane >> 4;
    f32x4 acc[4][4] = {};

    // staging: lane l covers row (tid>>3), source chunk (l&7)^(l>>3) (inverse swizzle)
    const int csrc = ((lane & 7) ^ (lane >> 3)) << 4;
    const char* gA = (const char*)A + (size_t)(m0 + (tid >> 3)) * (Dm * 2) + csrc;
    const char* gB = (const char*)Bw + (size_t)(n0 + (tid >> 3)) * (Dm * 2) + csrc;

    auto stage = [&](int buf, int ktn) {
        const char* a = gA + ktn * 128;           // BK*2 bytes per K-tile
        const char* b = gB + ktn * 128;
#pragma unroll
        for (int j = 0; j < 4; j++)               // A: 256 rows = 4 rounds of 64
            gld_lds16(a + (size_t)j * 64 * (Dm * 2), &sA[buf][0] + j * 4096 + wid * 512);
#pragma unroll
        for (int j = 0; j < 2; j++)               // B: 128 rows = 2 rounds of 64
            gld_lds16(b + (size_t)j * 64 * (Dm * 2), &sB[buf][0] + j * 4096 + wid * 512);
    };

    auto phase = [&](const char* rA, const char* rB, int q, bool dostage, int nbuf, int ktn) {
        bf16x8 af[2][2], bfr[4][2];
#pragma unroll
        for (int m2 = 0; m2 < 2; m2++) {
            const int row = wm * 64 + (q * 2 + m2) * 16 + lr;
            const int sw = row & 7;
            af[m2][0] = *(const bf16x8*)(rA + row * 128 + ((lg ^ sw) << 4));
            af[m2][1] = *(const bf16x8*)(rA + row * 128 + (((4 + lg) ^ sw) << 4));
        }
#pragma unroll
        for (int ni = 0; ni < 4; ni++) {
            const int row = wn * 64 + ni * 16 + lr;
            const int sw = row & 7;
            bfr[ni][0] = *(const bf16x8*)(rB + row * 128 + ((lg ^ sw) << 4));
            bfr[ni][1] = *(const bf16x8*)(rB + row * 128 + (((4 + lg) ^ sw) << 4));
        }
        if (dostage) stage(nbuf, ktn);
        __builtin_amdgcn_s_barrier();
        asm volatile("s_waitcnt lgkmcnt(0)" ::: "memory");
        __builtin_amdgcn_sched_barrier(0);
        __builtin_amdgcn_s_setprio(1);
#pragma unroll
        for (int m2 = 0; m2 < 2; m2++)
#pragma unroll
            for (int ni = 0; ni < 4; ni++) {
                acc[q * 2 + m2][ni] = __builtin_amdgcn_mfma_f32_16x16x32_bf16(
                    af[m2][0], bfr[ni][0], acc[q * 2 + m2][ni], 0, 0, 0);
                acc[q * 2 + m2][ni] = __builtin_amdgcn_mfma_f32_16x16x32_bf16(
                    af[m2][1], bfr[ni][1], acc[q * 2 + m2][ni], 0, 0, 0);
            }
        __builtin_amdgcn_s_setprio(0);
        __builtin_amdgcn_s_barrier();
    };

    stage(0, 0);
    int cur = 0;
    for (int kt = 0; kt < Dm / 64; kt++) {
        asm volatile("s_waitcnt vmcnt(0)" ::: "memory");   // tile kt's staging landed
        __builtin_amdgcn_s_barrier();                       // ...for ALL waves
        const char* rA = (const char*)&sA[cur][0];
        const char* rB = (const char*)&sB[cur][0];
        const bool st = (kt + 1 < Dm / 64);
        phase(rA, rB, 0, st, cur ^ 1, kt + 1);
        phase(rA, rB, 1, false, 0, 0);
        cur ^= 1;
    }

    // epilogue: scatter Q (pre-scaled), K, V^T (k'-permuted), + bias
#pragma unroll
    for (int mi = 0; mi < 4; mi++) {
        const int row0 = m0 + wm * 64 + mi * 16 + lg * 4;
#pragma unroll
        for (int ni = 0; ni < 4; ni++) {
            const int gn = n0 + wn * 64 + ni * 16 + lr;
            const int t = gn >> 10;
            const int n = gn & 1023;
            const int h = n >> 6, d = n & 63;
            const float bsv = (t == 0) ? bq[n] : (t == 1) ? bk[n] : bv[n];
#pragma unroll
            for (int r = 0; r < 4; r++) {
                const int row = row0 + r;
                const float v = acc[mi][ni][r] + bsv;
                const int bb = row >> 11;
                const int s = row & (S - 1);
                const size_t bh = (size_t)bb * H + h;
                if (t == 0) {
                    Qo[(bh * S + s) * DK + d] = f2b(v * 0.18033688011f);
                } else if (t == 1) {
                    Ko[(bh * S + s) * DK + d] = f2b(v);
                } else {
                    const int k5 = s & 31;
                    const int sp = (s & ~31) | ((k5 & 12) << 1) | ((k5 >> 4) << 2) | (k5 & 3);
                    Vto[(bh * DK + d) * S + sp] = f2b(v);
                }
            }
        }
    }
}

// ---- GEMM (m97 structure), used for the output projection ----
template <int MODE>
__global__ __launch_bounds__(256) void k_gemm(
    const unsigned short* __restrict__ A,
    const unsigned short* __restrict__ Bw,
    const float* __restrict__ bias0,
    float* __restrict__ Co)
{
    __shared__ unsigned short sA[128 * 32];
    __shared__ unsigned short sB[128 * 32];
    const int m0 = blockIdx.x * 128;
    const int gn0 = blockIdx.y * 128;
    const int tid = threadIdx.x;
    const int lane = tid & 63;
    const int wid = tid >> 6;
    const int wm = wid & 1, wn = wid >> 1;
    const int srow = tid >> 2;
    const int sc8 = (tid & 3) * 8;
    const int lr = lane & 15;
    const int lg = lane >> 4;
    f32x4 acc[4][4] = {};
    const unsigned short* Ag = A + (size_t)(m0 + srow) * Dm + sc8;
    const unsigned short* Bg = Bw + (size_t)(gn0 + srow) * Dm + sc8;
    unsigned short* const lA = sA + wid * 512;
    unsigned short* const lB = sB + wid * 512;
    for (int k0 = 0; k0 < Dm; k0 += 32) {
        __syncthreads();
        gld_lds16(Ag + k0, lA);
        gld_lds16(Ag + (size_t)64 * Dm + k0, lA + 2048);
        gld_lds16(Bg + k0, lB);
        gld_lds16(Bg + (size_t)64 * Dm + k0, lB + 2048);
        __syncthreads();
        bf16x8 af[4], bg[4];
#pragma unroll
        for (int mi = 0; mi < 4; mi++)
            af[mi] = *(const bf16x8*)&sA[(wm * 64 + mi * 16 + lr) * 32 + lg * 8];
#pragma unroll
        for (int ni = 0; ni < 4; ni++)
            bg[ni] = *(const bf16x8*)&sB[(wn * 64 + ni * 16 + lr) * 32 + lg * 8];
#pragma unroll
        for (int mi = 0; mi < 4; mi++)
#pragma unroll
            for (int ni = 0; ni < 4; ni++)
                acc[mi][ni] = __builtin_amdgcn_mfma_f32_16x16x32_bf16(af[mi], bg[ni], acc[mi][ni], 0, 0, 0);
    }
#pragma unroll
    for (int mi = 0; mi < 4; mi++) {
        const int row0 = m0 + wm * 64 + mi * 16 + lg * 4;
#pragma unroll
        for (int ni = 0; ni < 4; ni++) {
            const int gn = gn0 + wn * 64 + ni * 16 + lr;
            const float bsv = bias0[gn];
#pragma unroll
            for (int r = 0; r < 4; r++)
                Co[(size_t)(row0 + r) * Dm + gn] = acc[mi][ni][r] + bsv;
        }
    }
}

// ---- Flash attention (R10 config): swapped QK^T, exp2-domain softmax,
//      32 q-rows/wave, 8 waves/block, gld_lds dbuf.
//      launch_bounds(512,2): arg2=4 caps VGPR at 64 on this toolchain. ----
__global__ __launch_bounds__(512, 2) void k_attn(
    const unsigned short* __restrict__ Q, const unsigned short* __restrict__ K,
    const unsigned short* __restrict__ Vt, const unsigned char* __restrict__ mask,
    unsigned short* __restrict__ ctx)
{
    __shared__ unsigned short sK[2 * 4096];
    __shared__ unsigned short sV[2 * 4096];
    const int wg = blockIdx.x;
    const int sz = (wg & 7) * 64 + (wg >> 3);
    const int xt = sz & 7;
    const int bh = sz >> 3;
    const int bidx = bh >> 4, h = bh & 15;
    const int tid = threadIdx.x, lane = tid & 63, wid = tid >> 6;
    const int lr = lane & 15, lg = lane >> 4;
    const int qbase = xt * 256 + wid * 32;
    const size_t hoff = (size_t)bh * S * DK;
    const unsigned short* qp = Q + hoff + (size_t)(qbase + lr) * DK;
    const bf16x8 aqA0 = *(const bf16x8*)(qp + lg * 8);
    const bf16x8 aqA1 = *(const bf16x8*)(qp + 32 + lg * 8);
    const bf16x8 aqB0 = *(const bf16x8*)(qp + 16 * DK + lg * 8);
    const bf16x8 aqB1 = *(const bf16x8*)(qp + 16 * DK + 32 + lg * 8);
    const unsigned char* mrow = mask + bidx * S;
    f32x4 oA[4] = {}, oB[4] = {};
    f32x4 lvA = {}, lvB = {};
    const int rw = lane >> 3;
    const int row0 = wid * 8 + rw;
    const int csrc = ((lane & 7) ^ rw) << 4;
    const char* gK = (const char*)(K + hoff) + (size_t)row0 * 128 + csrc;
    const char* gV = (const char*)(Vt + hoff) + (size_t)row0 * (S * 2) + csrc;
    constexpr int NT = S / 64;
    unsigned short* const wK = sK + wid * 512;
    unsigned short* const wV = sV + wid * 512;

    gld_lds16(gK, wK);
    gld_lds16(gV, wV);
    unsigned char mb = mrow[lane];
    gK += 8192; gV += 128;

    auto body = [&](int t, const char* sKc, const char* sVc, int nbuf) {
        asm volatile("s_waitcnt vmcnt(0)" ::: "memory");
        __builtin_amdgcn_s_barrier();
        __builtin_amdgcn_sched_barrier(0);
        const unsigned char mbc = mb;
        if (t + 1 < NT) {
            gld_lds16(gK, wK + nbuf * 4096);
            gld_lds16(gV, wV + nbuf * 4096);
            mb = mrow[(t + 1) * 64 + lane];
            gK += 8192; gV += 128;
        }
        const unsigned long long bal = __ballot(mbc != 0);
        f32x4 zA[4], zB[4];
        __builtin_amdgcn_s_setprio(1);
#pragma unroll
        for (int nt = 0; nt < 4; nt++) {
            const int row = nt * 16 + lr;
            const int sw = (row & 7) << 4;
            const bf16x8 kf0 = *(const bf16x8*)(sKc + ((row * 128 + lg * 16) ^ sw));
            const bf16x8 kf1 = *(const bf16x8*)(sKc + ((row * 128 + 64 + lg * 16) ^ sw));
            f32x4 a = {};
            a = __builtin_amdgcn_mfma_f32_16x16x32_bf16(kf0, aqA0, a, 0, 0, 0);
            zA[nt] = __builtin_amdgcn_mfma_f32_16x16x32_bf16(kf1, aqA1, a, 0, 0, 0);
            f32x4 b = {};
            b = __builtin_amdgcn_mfma_f32_16x16x32_bf16(kf0, aqB0, b, 0, 0, 0);
            zB[nt] = __builtin_amdgcn_mfma_f32_16x16x32_bf16(kf1, aqB1, b, 0, 0, 0);
        }
        __builtin_amdgcn_s_setprio(0);
        if (bal) {
#pragma unroll
            for (int nt = 0; nt < 4; nt++)
#pragma unroll
                for (int r = 0; r < 4; r++)
                    if ((bal >> (nt * 16 + lg * 4 + r)) & 1) { zA[nt][r] = -1e9f; zB[nt][r] = -1e9f; }
        }
        union { unsigned u[4]; bf16x8 v; } wA0, wA1, wB0, wB1;
#pragma unroll
        for (int nt = 0; nt < 4; nt++) {
#pragma unroll
            for (int r = 0; r < 4; r++) zA[nt][r] = fexp2(zA[nt][r]);
            lvA += zA[nt];
        }
        wA0.u[0] = cvtpk(zA[0][0], zA[0][1]); wA0.u[1] = cvtpk(zA[0][2], zA[0][3]);
        wA0.u[2] = cvtpk(zA[1][0], zA[1][1]); wA0.u[3] = cvtpk(zA[1][2], zA[1][3]);
        wA1.u[0] = cvtpk(zA[2][0], zA[2][1]); wA1.u[1] = cvtpk(zA[2][2], zA[2][3]);
        wA1.u[2] = cvtpk(zA[3][0], zA[3][1]); wA1.u[3] = cvtpk(zA[3][2], zA[3][3]);
#pragma unroll
        for (int nt = 0; nt < 4; nt++) {
#pragma unroll
            for (int r = 0; r < 4; r++) zB[nt][r] = fexp2(zB[nt][r]);
            lvB += zB[nt];
        }
        wB0.u[0] = cvtpk(zB[0][0], zB[0][1]); wB0.u[1] = cvtpk(zB[0][2], zB[0][3]);
        wB0.u[2] = cvtpk(zB[1][0], zB[1][1]); wB0.u[3] = cvtpk(zB[1][2], zB[1][3]);
        wB1.u[0] = cvtpk(zB[2][0], zB[2][1]); wB1.u[1] = cvtpk(zB[2][2], zB[2][3]);
        wB1.u[2] = cvtpk(zB[3][0], zB[3][1]); wB1.u[3] = cvtpk(zB[3][2], zB[3][3]);
        __builtin_amdgcn_s_setprio(1);
#pragma unroll
        for (int dt = 0; dt < 4; dt++) {
            const int row = dt * 16 + lr;
            const int sw = (row & 7) << 4;
            const bf16x8 v0 = *(const bf16x8*)(sVc + ((row * 128 + lg * 16) ^ sw));
            const bf16x8 v1 = *(const bf16x8*)(sVc + ((row * 128 + 64 + lg * 16) ^ sw));
            oA[dt] = __builtin_amdgcn_mfma_f32_16x16x32_bf16(wA0.v, v0, oA[dt], 0, 0, 0);
            oA[dt] = __builtin_amdgcn_mfma_f32_16x16x32_bf16(wA1.v, v1, oA[dt], 0, 0, 0);
            oB[dt] = __builtin_amdgcn_mfma_f32_16x16x32_bf16(wB0.v, v0, oB[dt], 0, 0, 0);
            oB[dt] = __builtin_amdgcn_mfma_f32_16x16x32_bf16(wB1.v, v1, oB[dt], 0, 0, 0);
        }
        __builtin_amdgcn_s_setprio(0);
        asm volatile("s_waitcnt lgkmcnt(0)" ::: "memory");
    };

    const char* const sKb0 = (const char*)sK;
    const char* const sKb1 = sKb0 + 8192;
    const char* const sVb0 = (const char*)sV;
    const char* const sVb1 = sVb0 + 8192;
    for (int t = 0; t < NT; t += 2) {
        body(t,     sKb0, sVb0, 1);
        body(t + 1, sKb1, sVb1, 0);
    }

    float lsA = (lvA[0] + lvA[1]) + (lvA[2] + lvA[3]);
    lsA += __shfl_xor(lsA, 16, 64);
    lsA += __shfl_xor(lsA, 32, 64);
    float lsB = (lvB[0] + lvB[1]) + (lvB[2] + lvB[3]);
    lsB += __shfl_xor(lsB, 16, 64);
    lsB += __shfl_xor(lsB, 32, 64);
#pragma unroll
    for (int r = 0; r < 4; r++) {
        const float iA = 1.f / __shfl(lsA, lg * 4 + r, 16);
        const float iB = 1.f / __shfl(lsB, lg * 4 + r, 16);
        const int sA_ = qbase + lg * 4 + r;
#pragma unroll
        for (int dt = 0; dt < 4; dt++) {
            const int col = h * 64 + dt * 16 + lr;
            ctx[((size_t)bidx * S + sA_) * Dm + col]      = f2b(oA[dt][r] * iA);
            ctx[((size_t)bidx * S + sA_ + 16) * Dm + col] = f2b(oB[dt][r] * iB);
        }
    }
}

extern "C" void kernel_launch(void* const* d_in, const int* in_sizes, int n_in,
                              void* d_out, int out_size, void* d_ws, size_t ws_size,
                              hipStream_t stream)
{
    (void)in_sizes; (void)n_in; (void)out_size; (void)ws_size;
    const float* x  = (const float*)d_in[0];
    const float* Wq = (const float*)d_in[1];
    const float* bq = (const float*)d_in[2];
    const float* Wk = (const float*)d_in[3];
    const float* bk = (const float*)d_in[4];
    const float* Wv = (const float*)d_in[5];
    const float* bv = (const float*)d_in[6];
    const float* Wo = (const float*)d_in[7];
    const float* bo = (const float*)d_in[8];
    float* out = (float*)d_out;
    char* ws = (char*)d_ws;
    unsigned short* xb  = (unsigned short*)(ws);
    unsigned short* Wt  = (unsigned short*)(ws + ((size_t)16 << 20));
    unsigned short* Qb  = (unsigned short*)(ws + ((size_t)24 << 20));
    unsigned short* Kb  = (unsigned short*)(ws + ((size_t)40 << 20));
    unsigned short* Vtb = (unsigned short*)(ws + ((size_t)56 << 20));
    unsigned short* ctx = (unsigned short*)(ws + ((size_t)72 << 20));
    unsigned char*  msk = (unsigned char*)(ws + ((size_t)88 << 20));

    k_convx<<<dim3(M), dim3(256), 0, stream>>>(x, xb, msk);
    k_convw<<<dim3(Dm / 32, Dm / 32, 4), dim3(32, 8), 0, stream>>>(Wq, Wk, Wv, Wo, Wt);
    k_g0<<<dim3(M / 256, 3072 / 128), dim3(512), 0, stream>>>(
        xb, Wt, bq, bk, bv, Qb, Kb, Vtb);
    k_attn<<<dim3(Bz * H * (S / 256)), dim3(512), 0, stream>>>(Qb, Kb, Vtb, msk, ctx);
    k_gemm<1><<<dim3(M / 128, 1024 / 128), dim3(256), 0, stream>>>(
        ctx, Wt + (size_t)3 * Dm * Dm, bo, out);
}

// Round 13
// 201.197 us; speedup vs baseline: 1.0766x; 1.0766x over previous
//
#include <hip/hip_runtime.h>
#include <cstdint>
#include <cstddef>

static constexpr int Bz = 4, S = 2048, Dm = 1024, H = 16, DK = 64;
static constexpr int M = Bz * S;  // 8192

typedef __attribute__((ext_vector_type(8))) short bf16x8;
typedef __attribute__((ext_vector_type(4))) float f32x4;

__device__ __forceinline__ unsigned short f2b(float f) {
    unsigned u = __float_as_uint(f);
    return (unsigned short)((u + 0x7FFFu + ((u >> 16) & 1u)) >> 16);  // RNE
}

__device__ __forceinline__ unsigned cvtpk(float lo, float hi) {
    unsigned r;
    asm("v_cvt_pk_bf16_f32 %0, %1, %2" : "=v"(r) : "v"(lo), "v"(hi));
    return r;
}

// raw v_exp_f32 (exp2) — avoids OCML exp2f's range-check fixup code
__device__ __forceinline__ float fexp2(float x) {
#if __has_builtin(__builtin_amdgcn_exp2f)
    return __builtin_amdgcn_exp2f(x);
#else
    float r;
    asm("v_exp_f32 %0, %1" : "=v"(r) : "v"(x));
    return r;
#endif
}

__device__ __forceinline__ void gld_lds16(const void* g, void* l) {
    __builtin_amdgcn_global_load_lds(
        (const __attribute__((address_space(1))) unsigned int*)g,
        (__attribute__((address_space(3))) unsigned int*)l, 16, 0, 0);
}

// ---- K0a: x fp32 -> bf16, plus key-pad mask (any feature == 0) ----
__global__ __launch_bounds__(256) void k_convx(const float* __restrict__ x,
                                               unsigned short* __restrict__ xb,
                                               unsigned char* __restrict__ mask) {
    const int row = blockIdx.x;
    const int t = threadIdx.x;
    const float4 v = *(const float4*)(x + (size_t)row * Dm + t * 4);
    const bool z = (v.x == 0.f) | (v.y == 0.f) | (v.z == 0.f) | (v.w == 0.f);
    ushort4 o;
    o.x = f2b(v.x); o.y = f2b(v.y); o.z = f2b(v.z); o.w = f2b(v.w);
    *(ushort4*)(xb + (size_t)row * Dm + t * 4) = o;
    __shared__ int zf;
    if (t == 0) zf = 0;
    __syncthreads();
    if (z) zf = 1;
    __syncthreads();
    if (t == 0) mask[row] = (unsigned char)zf;
}

// ---- K0b: weights fp32 [K][N] -> bf16 transposed [N][K] ----
__global__ __launch_bounds__(256) void k_convw(const float* __restrict__ Wq, const float* __restrict__ Wk,
                                               const float* __restrict__ Wv, const float* __restrict__ Wo,
                                               unsigned short* __restrict__ Wt) {
    const float* W = (blockIdx.z == 0) ? Wq : (blockIdx.z == 1) ? Wk : (blockIdx.z == 2) ? Wv : Wo;
    unsigned short* o = Wt + (size_t)blockIdx.z * Dm * Dm;
    __shared__ float tile[32][33];
    const int k0 = blockIdx.x * 32, n0 = blockIdx.y * 32;
    const int tx = threadIdx.x, ty = threadIdx.y;
#pragma unroll
    for (int i = 0; i < 4; i++)
        tile[ty + 8 * i][tx] = W[(size_t)(k0 + ty + 8 * i) * Dm + n0 + tx];
    __syncthreads();
#pragma unroll
    for (int i = 0; i < 4; i++)
        o[(size_t)(n0 + ty + 8 * i) * Dm + k0 + tx] = f2b(tile[tx][ty + 8 * i]);
}

// ---- GEMM (m97 structure): C[M][N] = A[M][K] * Bw^T (Bw stored [N][K]) ----
// 2D grid (best measured; 1D XCD chunking regressed, 8-phase 256-tile port
// regressed -> occupancy/TLP loss).  MODE 0: Q pre-scaled, V^T k'-permuted.
template <int MODE>
__global__ __launch_bounds__(256) void k_gemm(
    const unsigned short* __restrict__ A,
    const unsigned short* __restrict__ Bw,
    const float* __restrict__ bias0, const float* __restrict__ bias1, const float* __restrict__ bias2,
    unsigned short* __restrict__ Qo, unsigned short* __restrict__ Ko,
    unsigned short* __restrict__ Vto, float* __restrict__ Co)
{
    __shared__ unsigned short sA[128 * 32];
    __shared__ unsigned short sB[128 * 32];
    const int m0 = blockIdx.x * 128;
    const int gn0 = blockIdx.y * 128;
    const int tid = threadIdx.x;
    const int lane = tid & 63;
    const int wid = tid >> 6;
    const int wm = wid & 1, wn = wid >> 1;
    const int srow = tid >> 2;
    const int sc8 = (tid & 3) * 8;
    const int lr = lane & 15;
    const int lg = lane >> 4;
    f32x4 acc[4][4] = {};
    const unsigned short* Ag = A + (size_t)(m0 + srow) * Dm + sc8;
    const unsigned short* Bg = Bw + (size_t)(gn0 + srow) * Dm + sc8;
    unsigned short* const lA = sA + wid * 512;
    unsigned short* const lB = sB + wid * 512;
    for (int k0 = 0; k0 < Dm; k0 += 32) {
        __syncthreads();
        gld_lds16(Ag + k0, lA);
        gld_lds16(Ag + (size_t)64 * Dm + k0, lA + 2048);
        gld_lds16(Bg + k0, lB);
        gld_lds16(Bg + (size_t)64 * Dm + k0, lB + 2048);
        __syncthreads();
        bf16x8 af[4], bg[4];
#pragma unroll
        for (int mi = 0; mi < 4; mi++)
            af[mi] = *(const bf16x8*)&sA[(wm * 64 + mi * 16 + lr) * 32 + lg * 8];
#pragma unroll
        for (int ni = 0; ni < 4; ni++)
            bg[ni] = *(const bf16x8*)&sB[(wn * 64 + ni * 16 + lr) * 32 + lg * 8];
#pragma unroll
        for (int mi = 0; mi < 4; mi++)
#pragma unroll
            for (int ni = 0; ni < 4; ni++)
                acc[mi][ni] = __builtin_amdgcn_mfma_f32_16x16x32_bf16(af[mi], bg[ni], acc[mi][ni], 0, 0, 0);
    }
#pragma unroll
    for (int mi = 0; mi < 4; mi++) {
        const int row0 = m0 + wm * 64 + mi * 16 + lg * 4;
#pragma unroll
        for (int ni = 0; ni < 4; ni++) {
            const int gn = gn0 + wn * 64 + ni * 16 + lr;
            const int t = gn >> 10;
            const int n = gn & 1023;
            const int h = n >> 6, d = n & 63;
            const float bsv = (MODE == 0)
                ? ((t == 0) ? bias0[n] : (t == 1) ? bias1[n] : bias2[n])
                : bias0[gn];
#pragma unroll
            for (int r = 0; r < 4; r++) {
                const int row = row0 + r;
                const float v = acc[mi][ni][r] + bsv;
                if (MODE == 0) {
                    const int bb = row >> 11;
                    const int s = row & (S - 1);
                    const size_t bh = (size_t)bb * H + h;
                    if (t == 0) {
                        // fold softmax scale * log2(e) into Q
                        Qo[(bh * S + s) * DK + d] = f2b(v * 0.18033688011f);
                    } else if (t == 1) {
                        Ko[(bh * S + s) * DK + d] = f2b(v);
                    } else {
                        const int k5 = s & 31;
                        const int sp = (s & ~31) | ((k5 & 12) << 1) | ((k5 >> 4) << 2) | (k5 & 3);
                        Vto[(bh * DK + d) * S + sp] = f2b(v);
                    }
                } else {
                    Co[(size_t)row * Dm + gn] = v;
                }
            }
        }
    }
}

// ---- Flash attention (R8 best-known config): swapped QK^T, exp2-domain
//      softmax (scale folded in Q), 32 q-rows/wave, 4 waves/block, raw
//      v_exp_f32, gld_lds dbuf.  + mask hoisted to wave-uniform aggregate
//      (per-tile ballot only under never-taken anymask branch).
//      launch_bounds(256,2): arg2=4 caps VGPR at 64 -> spills. ----
__global__ __launch_bounds__(256, 2) void k_attn(
    const unsigned short* __restrict__ Q, const unsigned short* __restrict__ K,
    const unsigned short* __restrict__ Vt, const unsigned char* __restrict__ mask,
    unsigned short* __restrict__ ctx)
{
    __shared__ unsigned short sK[2 * 4096];  // [buf][64 k-rows][64 d], XOR-swizzled
    __shared__ unsigned short sV[2 * 4096];  // [buf][64 d-rows][64 k'], XOR-swizzled
    // XCD-aware swizzle: 1024 blocks (1024 % 8 == 0 -> bijective)
    const int wg = blockIdx.x;
    const int sz = (wg & 7) * 128 + (wg >> 3);
    const int xt = sz & 15;       // q-tile (128 rows)
    const int bh = sz >> 4;       // head index
    const int bidx = bh >> 4, h = bh & 15;
    const int tid = threadIdx.x, lane = tid & 63, wid = tid >> 6;  // 4 waves
    const int lr = lane & 15, lg = lane >> 4;
    const int qbase = xt * 128 + wid * 32;
    const size_t hoff = (size_t)bh * S * DK;
    const unsigned char* mrow = mask + bidx * S;
    // wave-uniform mask aggregate: 2 coalesced uint4 loads cover all 2048 bytes
    const uint4 mza = *(const uint4*)(mrow + lane * 32);
    const uint4 mzb = *(const uint4*)(mrow + lane * 32 + 16);
    const bool anymask =
        __ballot((mza.x | mza.y | mza.z | mza.w | mzb.x | mzb.y | mzb.z | mzb.w) != 0) != 0ull;
    const unsigned short* qp = Q + hoff + (size_t)(qbase + lr) * DK;
    const bf16x8 aqA0 = *(const bf16x8*)(qp + lg * 8);
    const bf16x8 aqA1 = *(const bf16x8*)(qp + 32 + lg * 8);
    const bf16x8 aqB0 = *(const bf16x8*)(qp + 16 * DK + lg * 8);
    const bf16x8 aqB1 = *(const bf16x8*)(qp + 16 * DK + 32 + lg * 8);
    f32x4 oA[4] = {}, oB[4] = {};
    f32x4 lvA = {}, lvB = {};
    // staging: wave wid covers rows wid*16 + (lane>>3) (+8 on second gld)
    const int rw = lane >> 3;                 // 0..7
    const int row0 = wid * 16 + rw;
    const int csrc = ((lane & 7) ^ rw) << 4;  // inverse-XOR-swizzled source chunk
    const char* gK0 = (const char*)(K + hoff) + (size_t)row0 * 128 + csrc;
    const char* gK1 = gK0 + 8 * 128;
    const char* gV0 = (const char*)(Vt + hoff) + (size_t)row0 * (S * 2) + csrc;
    const char* gV1 = gV0 + (size_t)8 * (S * 2);
    constexpr int NT = S / 64;  // 32
    unsigned short* const wK = sK + wid * 1024;  // per-wave K dest (2KB)
    unsigned short* const wV = sV + wid * 1024;

    // prologue: tile 0 -> buf 0
    gld_lds16(gK0, wK);        gld_lds16(gK1, wK + 512);
    gld_lds16(gV0, wV);        gld_lds16(gV1, wV + 512);
    gK0 += 8192; gK1 += 8192; gV0 += 128; gV1 += 128;

    auto body = [&](int t, const char* sKc, const char* sVc, int nbuf) {
        asm volatile("s_waitcnt vmcnt(0)" ::: "memory");
        __builtin_amdgcn_s_barrier();
        __builtin_amdgcn_sched_barrier(0);
        if (t + 1 < NT) {
            gld_lds16(gK0, wK + nbuf * 4096);  gld_lds16(gK1, wK + nbuf * 4096 + 512);
            gld_lds16(gV0, wV + nbuf * 4096);  gld_lds16(gV1, wV + nbuf * 4096 + 512);
            gK0 += 8192; gK1 += 8192; gV0 += 128; gV1 += 128;
        }
        // QK^T swapped: A = K rows, B = Q rows.  C[k][q]: lane owns q = lr.
        f32x4 zA[4], zB[4];
        __builtin_amdgcn_s_setprio(1);
#pragma unroll
        for (int nt = 0; nt < 4; nt++) {
            const int row = nt * 16 + lr;
            const int sw = (row & 7) << 4;
            const bf16x8 kf0 = *(const bf16x8*)(sKc + ((row * 128 + lg * 16) ^ sw));
            const bf16x8 kf1 = *(const bf16x8*)(sKc + ((row * 128 + 64 + lg * 16) ^ sw));
            f32x4 a = {};
            a = __builtin_amdgcn_mfma_f32_16x16x32_bf16(kf0, aqA0, a, 0, 0, 0);
            zA[nt] = __builtin_amdgcn_mfma_f32_16x16x32_bf16(kf1, aqA1, a, 0, 0, 0);
            f32x4 b = {};
            b = __builtin_amdgcn_mfma_f32_16x16x32_bf16(kf0, aqB0, b, 0, 0, 0);
            zB[nt] = __builtin_amdgcn_mfma_f32_16x16x32_bf16(kf1, aqB1, b, 0, 0, 0);
        }
        __builtin_amdgcn_s_setprio(0);
        if (anymask) {             // wave-uniform; never taken for this data
            const unsigned long long bal = __ballot(mrow[t * 64 + lane] != 0);
            if (bal) {
#pragma unroll
                for (int nt = 0; nt < 4; nt++)
#pragma unroll
                    for (int r = 0; r < 4; r++)
                        if ((bal >> (nt * 16 + lg * 4 + r)) & 1) { zA[nt][r] = -1e9f; zB[nt][r] = -1e9f; }
            }
        }
        // A-half first (frees zA before zB's exp): p = exp2(z); lane-local sum
        union { unsigned u[4]; bf16x8 v; } wA0, wA1, wB0, wB1;
#pragma unroll
        for (int nt = 0; nt < 4; nt++) {
#pragma unroll
            for (int r = 0; r < 4; r++) zA[nt][r] = fexp2(zA[nt][r]);
            lvA += zA[nt];
        }
        wA0.u[0] = cvtpk(zA[0][0], zA[0][1]); wA0.u[1] = cvtpk(zA[0][2], zA[0][3]);
        wA0.u[2] = cvtpk(zA[1][0], zA[1][1]); wA0.u[3] = cvtpk(zA[1][2], zA[1][3]);
        wA1.u[0] = cvtpk(zA[2][0], zA[2][1]); wA1.u[1] = cvtpk(zA[2][2], zA[2][3]);
        wA1.u[2] = cvtpk(zA[3][0], zA[3][1]); wA1.u[3] = cvtpk(zA[3][2], zA[3][3]);
#pragma unroll
        for (int nt = 0; nt < 4; nt++) {
#pragma unroll
            for (int r = 0; r < 4; r++) zB[nt][r] = fexp2(zB[nt][r]);
            lvB += zB[nt];
        }
        wB0.u[0] = cvtpk(zB[0][0], zB[0][1]); wB0.u[1] = cvtpk(zB[0][2], zB[0][3]);
        wB0.u[2] = cvtpk(zB[1][0], zB[1][1]); wB0.u[3] = cvtpk(zB[1][2], zB[1][3]);
        wB1.u[0] = cvtpk(zB[2][0], zB[2][1]); wB1.u[1] = cvtpk(zB[2][2], zB[2][3]);
        wB1.u[2] = cvtpk(zB[3][0], zB[3][1]); wB1.u[3] = cvtpk(zB[3][2], zB[3][3]);
        // PV: A = P (q rows), B = V^T (d rows), contraction over permuted k'
        __builtin_amdgcn_s_setprio(1);
#pragma unroll
        for (int dt = 0; dt < 4; dt++) {
            const int row = dt * 16 + lr;
            const int sw = (row & 7) << 4;
            const bf16x8 v0 = *(const bf16x8*)(sVc + ((row * 128 + lg * 16) ^ sw));
            const bf16x8 v1 = *(const bf16x8*)(sVc + ((row * 128 + 64 + lg * 16) ^ sw));
            oA[dt] = __builtin_amdgcn_mfma_f32_16x16x32_bf16(wA0.v, v0, oA[dt], 0, 0, 0);
            oA[dt] = __builtin_amdgcn_mfma_f32_16x16x32_bf16(wA1.v, v1, oA[dt], 0, 0, 0);
            oB[dt] = __builtin_amdgcn_mfma_f32_16x16x32_bf16(wB0.v, v0, oB[dt], 0, 0, 0);
            oB[dt] = __builtin_amdgcn_mfma_f32_16x16x32_bf16(wB1.v, v1, oB[dt], 0, 0, 0);
        }
        __builtin_amdgcn_s_setprio(0);
        asm volatile("s_waitcnt lgkmcnt(0)" ::: "memory");  // drain reads before buf restage
    };

    const char* const sKb0 = (const char*)sK;
    const char* const sKb1 = sKb0 + 8192;
    const char* const sVb0 = (const char*)sV;
    const char* const sVb1 = sVb0 + 8192;
    for (int t = 0; t < NT; t += 2) {
        body(t,     sKb0, sVb0, 1);
        body(t + 1, sKb1, sVb1, 0);
    }

    // final cross-lane sum reduce, normalize, store both q-halves
    float lsA = (lvA[0] + lvA[1]) + (lvA[2] + lvA[3]);
    lsA += __shfl_xor(lsA, 16, 64);
    lsA += __shfl_xor(lsA, 32, 64);
    float lsB = (lvB[0] + lvB[1]) + (lvB[2] + lvB[3]);
    lsB += __shfl_xor(lsB, 16, 64);
    lsB += __shfl_xor(lsB, 32, 64);
#pragma unroll
    for (int r = 0; r < 4; r++) {
        const float iA = 1.f / __shfl(lsA, lg * 4 + r, 16);
        const float iB = 1.f / __shfl(lsB, lg * 4 + r, 16);
        const int sA_ = qbase + lg * 4 + r;
#pragma unroll
        for (int dt = 0; dt < 4; dt++) {
            const int col = h * 64 + dt * 16 + lr;
            ctx[((size_t)bidx * S + sA_) * Dm + col]      = f2b(oA[dt][r] * iA);
            ctx[((size_t)bidx * S + sA_ + 16) * Dm + col] = f2b(oB[dt][r] * iB);
        }
    }
}

extern "C" void kernel_launch(void* const* d_in, const int* in_sizes, int n_in,
                              void* d_out, int out_size, void* d_ws, size_t ws_size,
                              hipStream_t stream)
{
    (void)in_sizes; (void)n_in; (void)out_size; (void)ws_size;
    const float* x  = (const float*)d_in[0];
    const float* Wq = (const float*)d_in[1];
    const float* bq = (const float*)d_in[2];
    const float* Wk = (const float*)d_in[3];
    const float* bk = (const float*)d_in[4];
    const float* Wv = (const float*)d_in[5];
    const float* bv = (const float*)d_in[6];
    const float* Wo = (const float*)d_in[7];
    const float* bo = (const float*)d_in[8];
    float* out = (float*)d_out;
    char* ws = (char*)d_ws;
    unsigned short* xb  = (unsigned short*)(ws);
    unsigned short* Wt  = (unsigned short*)(ws + ((size_t)16 << 20));
    unsigned short* Qb  = (unsigned short*)(ws + ((size_t)24 << 20));
    unsigned short* Kb  = (unsigned short*)(ws + ((size_t)40 << 20));
    unsigned short* Vtb = (unsigned short*)(ws + ((size_t)56 << 20));
    unsigned short* ctx = (unsigned short*)(ws + ((size_t)72 << 20));
    unsigned char*  msk = (unsigned char*)(ws + ((size_t)88 << 20));

    k_convx<<<dim3(M), dim3(256), 0, stream>>>(x, xb, msk);
    k_convw<<<dim3(Dm / 32, Dm / 32, 4), dim3(32, 8), 0, stream>>>(Wq, Wk, Wv, Wo, Wt);
    k_gemm<0><<<dim3(M / 128, 3072 / 128), dim3(256), 0, stream>>>(
        xb, Wt, bq, bk, bv, Qb, Kb, Vtb, nullptr);
    k_attn<<<dim3(Bz * H * (S / 128)), dim3(256), 0, stream>>>(Qb, Kb, Vtb, msk, ctx);
    k_gemm<1><<<dim3(M / 128, 1024 / 128), dim3(256), 0, stream>>>(
        ctx, Wt + (size_t)3 * Dm * Dm, bo, nullptr, nullptr, nullptr, nullptr, nullptr, out);
}

// Round 14
// 196.563 us; speedup vs baseline: 1.1020x; 1.0236x over previous
//
#include <hip/hip_runtime.h>
#include <cstdint>
#include <cstddef>

static constexpr int Bz = 4, S = 2048, Dm = 1024, H = 16, DK = 64;
static constexpr int M = Bz * S;  // 8192

typedef __attribute__((ext_vector_type(8))) short bf16x8;
typedef __attribute__((ext_vector_type(4))) float f32x4;

__device__ __forceinline__ unsigned short f2b(float f) {
    unsigned u = __float_as_uint(f);
    return (unsigned short)((u + 0x7FFFu + ((u >> 16) & 1u)) >> 16);  // RNE
}

__device__ __forceinline__ unsigned cvtpk(float lo, float hi) {
    unsigned r;
    asm("v_cvt_pk_bf16_f32 %0, %1, %2" : "=v"(r) : "v"(lo), "v"(hi));
    return r;
}

// raw v_exp_f32 (exp2) — avoids OCML exp2f's range-check fixup code
__device__ __forceinline__ float fexp2(float x) {
#if __has_builtin(__builtin_amdgcn_exp2f)
    return __builtin_amdgcn_exp2f(x);
#else
    float r;
    asm("v_exp_f32 %0, %1" : "=v"(r) : "v"(x));
    return r;
#endif
}

__device__ __forceinline__ void gld_lds16(const void* g, void* l) {
    __builtin_amdgcn_global_load_lds(
        (const __attribute__((address_space(1))) unsigned int*)g,
        (__attribute__((address_space(3))) unsigned int*)l, 16, 0, 0);
}

// ---- K0: fused input-convert (+mask) and weight-transpose ----
// blocks [0, 8192):  x fp32 -> bf16 row + pad-mask byte
// blocks [8192, 12288): weights fp32 [K][N] -> bf16 [N][K], 4 matrices
__global__ __launch_bounds__(256) void k_conv(const float* __restrict__ x,
                                              const float* __restrict__ Wq, const float* __restrict__ Wk,
                                              const float* __restrict__ Wv, const float* __restrict__ Wo,
                                              unsigned short* __restrict__ xb,
                                              unsigned char* __restrict__ mask,
                                              unsigned short* __restrict__ Wt) {
    const int bid = blockIdx.x;
    const int tid = threadIdx.x;
    if (bid < M) {
        const int row = bid;
        const float4 v = *(const float4*)(x + (size_t)row * Dm + tid * 4);
        const bool z = (v.x == 0.f) | (v.y == 0.f) | (v.z == 0.f) | (v.w == 0.f);
        ushort4 o;
        o.x = f2b(v.x); o.y = f2b(v.y); o.z = f2b(v.z); o.w = f2b(v.w);
        *(ushort4*)(xb + (size_t)row * Dm + tid * 4) = o;
        __shared__ int zf;
        if (tid == 0) zf = 0;
        __syncthreads();
        if (z) zf = 1;
        __syncthreads();
        if (tid == 0) mask[row] = (unsigned char)zf;
    } else {
        const int wb = bid - M;
        const int zidx = wb >> 10;           // 1024 blocks per matrix
        const int rem = wb & 1023;
        const int k0 = (rem & 31) * 32, n0 = (rem >> 5) * 32;
        const float* W = (zidx == 0) ? Wq : (zidx == 1) ? Wk : (zidx == 2) ? Wv : Wo;
        unsigned short* o = Wt + (size_t)zidx * Dm * Dm;
        __shared__ float tile[32][33];
        const int tx = tid & 31, ty = tid >> 5;
#pragma unroll
        for (int i = 0; i < 4; i++)
            tile[ty + 8 * i][tx] = W[(size_t)(k0 + ty + 8 * i) * Dm + n0 + tx];
        __syncthreads();
#pragma unroll
        for (int i = 0; i < 4; i++)
            o[(size_t)(n0 + ty + 8 * i) * Dm + k0 + tx] = f2b(tile[tx][ty + 8 * i]);
    }
}

// ---- GEMM (m97 structure): C[M][N] = A[M][K] * Bw^T (Bw stored [N][K]) ----
// MODE 0: Q pre-scaled by 1/sqrt(dk)*log2(e); V^T with k'-permutation baked in.
template <int MODE>
__global__ __launch_bounds__(256) void k_gemm(
    const unsigned short* __restrict__ A,
    const unsigned short* __restrict__ Bw,
    const float* __restrict__ bias0, const float* __restrict__ bias1, const float* __restrict__ bias2,
    unsigned short* __restrict__ Qo, unsigned short* __restrict__ Ko,
    unsigned short* __restrict__ Vto, float* __restrict__ Co)
{
    __shared__ unsigned short sA[128 * 32];
    __shared__ unsigned short sB[128 * 32];
    const int m0 = blockIdx.x * 128;
    const int gn0 = blockIdx.y * 128;
    const int tid = threadIdx.x;
    const int lane = tid & 63;
    const int wid = tid >> 6;
    const int wm = wid & 1, wn = wid >> 1;
    const int srow = tid >> 2;
    const int sc8 = (tid & 3) * 8;
    const int lr = lane & 15;
    const int lg = lane >> 4;
    f32x4 acc[4][4] = {};
    const unsigned short* Ag = A + (size_t)(m0 + srow) * Dm + sc8;
    const unsigned short* Bg = Bw + (size_t)(gn0 + srow) * Dm + sc8;
    unsigned short* const lA = sA + wid * 512;
    unsigned short* const lB = sB + wid * 512;
    for (int k0 = 0; k0 < Dm; k0 += 32) {
        __syncthreads();
        gld_lds16(Ag + k0, lA);
        gld_lds16(Ag + (size_t)64 * Dm + k0, lA + 2048);
        gld_lds16(Bg + k0, lB);
        gld_lds16(Bg + (size_t)64 * Dm + k0, lB + 2048);
        __syncthreads();
        bf16x8 af[4], bg[4];
#pragma unroll
        for (int mi = 0; mi < 4; mi++)
            af[mi] = *(const bf16x8*)&sA[(wm * 64 + mi * 16 + lr) * 32 + lg * 8];
#pragma unroll
        for (int ni = 0; ni < 4; ni++)
            bg[ni] = *(const bf16x8*)&sB[(wn * 64 + ni * 16 + lr) * 32 + lg * 8];
#pragma unroll
        for (int mi = 0; mi < 4; mi++)
#pragma unroll
            for (int ni = 0; ni < 4; ni++)
                acc[mi][ni] = __builtin_amdgcn_mfma_f32_16x16x32_bf16(af[mi], bg[ni], acc[mi][ni], 0, 0, 0);
    }
#pragma unroll
    for (int mi = 0; mi < 4; mi++) {
        const int row0 = m0 + wm * 64 + mi * 16 + lg * 4;
#pragma unroll
        for (int ni = 0; ni < 4; ni++) {
            const int gn = gn0 + wn * 64 + ni * 16 + lr;
            const int t = gn >> 10;
            const int n = gn & 1023;
            const int h = n >> 6, d = n & 63;
            const float bsv = (MODE == 0)
                ? ((t == 0) ? bias0[n] : (t == 1) ? bias1[n] : bias2[n])
                : bias0[gn];
#pragma unroll
            for (int r = 0; r < 4; r++) {
                const int row = row0 + r;
                const float v = acc[mi][ni][r] + bsv;
                if (MODE == 0) {
                    const int bb = row >> 11;
                    const int s = row & (S - 1);
                    const size_t bh = (size_t)bb * H + h;
                    if (t == 0) {
                        Qo[(bh * S + s) * DK + d] = f2b(v * 0.18033688011f);
                    } else if (t == 1) {
                        Ko[(bh * S + s) * DK + d] = f2b(v);
                    } else {
                        const int k5 = s & 31;
                        const int sp = (s & ~31) | ((k5 & 12) << 1) | ((k5 >> 4) << 2) | (k5 & 3);
                        Vto[(bh * DK + d) * S + sp] = f2b(v);
                    }
                } else {
                    Co[(size_t)row * Dm + gn] = v;
                }
            }
        }
    }
}

// ---- Flash attention, KVBLK=32: swapped QK^T, exp2-domain softmax,
//      32 q-rows/wave, 4 waves/block, LDS 16KB (occupancy lever).
//      K: [32 rows][64 d] rows XOR-swz (row&7 on 8 chunks);
//      V: [64 d-rows][32 k'] rows XOR-swz ((row>>1)&3 on 4 chunks).
//      launch_bounds(256,2): arg2=4 caps VGPR at 64 -> spills. ----
__global__ __launch_bounds__(256, 2) void k_attn(
    const unsigned short* __restrict__ Q, const unsigned short* __restrict__ K,
    const unsigned short* __restrict__ Vt, const unsigned char* __restrict__ mask,
    unsigned short* __restrict__ ctx)
{
    __shared__ unsigned short sK[2 * 2048];  // [buf][32 rows][64 d]
    __shared__ unsigned short sV[2 * 2048];  // [buf][64 d-rows][32 k']
    // XCD-aware swizzle: 1024 blocks (1024 % 8 == 0 -> bijective)
    const int wg = blockIdx.x;
    const int sz = (wg & 7) * 128 + (wg >> 3);
    const int xt = sz & 15;       // q-tile (128 rows)
    const int bh = sz >> 4;       // head index
    const int bidx = bh >> 4, h = bh & 15;
    const int tid = threadIdx.x, lane = tid & 63, wid = tid >> 6;  // 4 waves
    const int lr = lane & 15, lg = lane >> 4;
    const int qbase = xt * 128 + wid * 32;
    const size_t hoff = (size_t)bh * S * DK;
    const unsigned char* mrow = mask + bidx * S;
    // wave-uniform mask aggregate
    const uint4 mza = *(const uint4*)(mrow + lane * 32);
    const uint4 mzb = *(const uint4*)(mrow + lane * 32 + 16);
    const bool anymask =
        __ballot((mza.x | mza.y | mza.z | mza.w | mzb.x | mzb.y | mzb.z | mzb.w) != 0) != 0ull;
    const unsigned short* qp = Q + hoff + (size_t)(qbase + lr) * DK;
    const bf16x8 aqA0 = *(const bf16x8*)(qp + lg * 8);
    const bf16x8 aqA1 = *(const bf16x8*)(qp + 32 + lg * 8);
    const bf16x8 aqB0 = *(const bf16x8*)(qp + 16 * DK + lg * 8);
    const bf16x8 aqB1 = *(const bf16x8*)(qp + 16 * DK + 32 + lg * 8);
    f32x4 oA[4] = {}, oB[4] = {};
    f32x4 lvA = {}, lvB = {};
    // K staging: wave wid covers rows wid*8 + (lane>>3); src chunk (lane&7)^rw
    const int rwk = lane >> 3;
    const int csK = ((lane & 7) ^ rwk) << 4;
    const char* gK = (const char*)(K + hoff) + (size_t)(wid * 8 + rwk) * 128 + csK;
    // V staging: wave wid covers d-rows wid*16 + (lane>>2); src chunk (lane&3)^((rv>>1)&3)
    const int rv = lane >> 2;
    const int csV = ((lane & 3) ^ ((rv >> 1) & 3)) << 4;
    const char* gV = (const char*)(Vt + hoff) + (size_t)(wid * 16 + rv) * (S * 2) + csV;
    constexpr int NT = S / 32;  // 64
    unsigned short* const wKd = sK + wid * 512;  // lane-contiguous 1KB per wave
    unsigned short* const wVd = sV + wid * 512;

    // prologue: tile 0 -> buf 0
    gld_lds16(gK, wKd);
    gld_lds16(gV, wVd);
    gK += 4096; gV += 64;

    auto body = [&](int t, const char* sKc, const char* sVc, int nbuf) {
        asm volatile("s_waitcnt vmcnt(0)" ::: "memory");
        __builtin_amdgcn_s_barrier();
        __builtin_amdgcn_sched_barrier(0);
        if (t + 1 < NT) {
            gld_lds16(gK, wKd + nbuf * 2048);
            gld_lds16(gV, wVd + nbuf * 2048);
            gK += 4096; gV += 64;
        }
        // QK^T swapped: A = K rows, B = Q rows.  C[k][q]: lane owns q = lr.
        f32x4 zA[2], zB[2];
        __builtin_amdgcn_s_setprio(1);
#pragma unroll
        for (int nt = 0; nt < 2; nt++) {
            const int row = nt * 16 + lr;
            const int sw = (row & 7) << 4;
            const bf16x8 kf0 = *(const bf16x8*)(sKc + ((row * 128 + lg * 16) ^ sw));
            const bf16x8 kf1 = *(const bf16x8*)(sKc + ((row * 128 + 64 + lg * 16) ^ sw));
            f32x4 a = {};
            a = __builtin_amdgcn_mfma_f32_16x16x32_bf16(kf0, aqA0, a, 0, 0, 0);
            zA[nt] = __builtin_amdgcn_mfma_f32_16x16x32_bf16(kf1, aqA1, a, 0, 0, 0);
            f32x4 b = {};
            b = __builtin_amdgcn_mfma_f32_16x16x32_bf16(kf0, aqB0, b, 0, 0, 0);
            zB[nt] = __builtin_amdgcn_mfma_f32_16x16x32_bf16(kf1, aqB1, b, 0, 0, 0);
        }
        __builtin_amdgcn_s_setprio(0);
        if (anymask) {             // wave-uniform; never taken for this data
            const unsigned long long bal =
                __ballot(mrow[t * 32 + (lane & 31)] != 0) & 0xFFFFFFFFull;
            if (bal) {
#pragma unroll
                for (int nt = 0; nt < 2; nt++)
#pragma unroll
                    for (int r = 0; r < 4; r++)
                        if ((bal >> (nt * 16 + lg * 4 + r)) & 1) { zA[nt][r] = -1e9f; zB[nt][r] = -1e9f; }
            }
        }
        // p = exp2(z); lane-local sum; pack to k' = lg*8 + nt*4 + r
        union { unsigned u[4]; bf16x8 v; } wA0, wB0;
#pragma unroll
        for (int nt = 0; nt < 2; nt++) {
#pragma unroll
            for (int r = 0; r < 4; r++) zA[nt][r] = fexp2(zA[nt][r]);
            lvA += zA[nt];
        }
        wA0.u[0] = cvtpk(zA[0][0], zA[0][1]); wA0.u[1] = cvtpk(zA[0][2], zA[0][3]);
        wA0.u[2] = cvtpk(zA[1][0], zA[1][1]); wA0.u[3] = cvtpk(zA[1][2], zA[1][3]);
#pragma unroll
        for (int nt = 0; nt < 2; nt++) {
#pragma unroll
            for (int r = 0; r < 4; r++) zB[nt][r] = fexp2(zB[nt][r]);
            lvB += zB[nt];
        }
        wB0.u[0] = cvtpk(zB[0][0], zB[0][1]); wB0.u[1] = cvtpk(zB[0][2], zB[0][3]);
        wB0.u[2] = cvtpk(zB[1][0], zB[1][1]); wB0.u[3] = cvtpk(zB[1][2], zB[1][3]);
        // PV: A = P (q rows), B = V^T (d rows), contraction over permuted k'
        __builtin_amdgcn_s_setprio(1);
#pragma unroll
        for (int dt = 0; dt < 4; dt++) {
            const int row = dt * 16 + lr;
            const int sw = (row >> 1) & 3;
            const bf16x8 v0 = *(const bf16x8*)(sVc + row * 64 + ((lg ^ sw) << 4));
            oA[dt] = __builtin_amdgcn_mfma_f32_16x16x32_bf16(wA0.v, v0, oA[dt], 0, 0, 0);
            oB[dt] = __builtin_amdgcn_mfma_f32_16x16x32_bf16(wB0.v, v0, oB[dt], 0, 0, 0);
        }
        __builtin_amdgcn_s_setprio(0);
        asm volatile("s_waitcnt lgkmcnt(0)" ::: "memory");  // drain reads before buf restage
    };

    const char* const sKb0 = (const char*)sK;
    const char* const sKb1 = sKb0 + 4096;
    const char* const sVb0 = (const char*)sV;
    const char* const sVb1 = sVb0 + 4096;
    for (int t = 0; t < NT; t += 2) {
        body(t,     sKb0, sVb0, 1);
        body(t + 1, sKb1, sVb1, 0);
    }

    // final cross-lane sum reduce, normalize, store both q-halves
    float lsA = (lvA[0] + lvA[1]) + (lvA[2] + lvA[3]);
    lsA += __shfl_xor(lsA, 16, 64);
    lsA += __shfl_xor(lsA, 32, 64);
    float lsB = (lvB[0] + lvB[1]) + (lvB[2] + lvB[3]);
    lsB += __shfl_xor(lsB, 16, 64);
    lsB += __shfl_xor(lsB, 32, 64);
#pragma unroll
    for (int r = 0; r < 4; r++) {
        const float iA = 1.f / __shfl(lsA, lg * 4 + r, 16);
        const float iB = 1.f / __shfl(lsB, lg * 4 + r, 16);
        const int sA_ = qbase + lg * 4 + r;
#pragma unroll
        for (int dt = 0; dt < 4; dt++) {
            const int col = h * 64 + dt * 16 + lr;
            ctx[((size_t)bidx * S + sA_) * Dm + col]      = f2b(oA[dt][r] * iA);
            ctx[((size_t)bidx * S + sA_ + 16) * Dm + col] = f2b(oB[dt][r] * iB);
        }
    }
}

extern "C" void kernel_launch(void* const* d_in, const int* in_sizes, int n_in,
                              void* d_out, int out_size, void* d_ws, size_t ws_size,
                              hipStream_t stream)
{
    (void)in_sizes; (void)n_in; (void)out_size; (void)ws_size;
    const float* x  = (const float*)d_in[0];
    const float* Wq = (const float*)d_in[1];
    const float* bq = (const float*)d_in[2];
    const float* Wk = (const float*)d_in[3];
    const float* bk = (const float*)d_in[4];
    const float* Wv = (const float*)d_in[5];
    const float* bv = (const float*)d_in[6];
    const float* Wo = (const float*)d_in[7];
    const float* bo = (const float*)d_in[8];
    float* out = (float*)d_out;
    char* ws = (char*)d_ws;
    unsigned short* xb  = (unsigned short*)(ws);
    unsigned short* Wt  = (unsigned short*)(ws + ((size_t)16 << 20));
    unsigned short* Qb  = (unsigned short*)(ws + ((size_t)24 << 20));
    unsigned short* Kb  = (unsigned short*)(ws + ((size_t)40 << 20));
    unsigned short* Vtb = (unsigned short*)(ws + ((size_t)56 << 20));
    unsigned short* ctx = (unsigned short*)(ws + ((size_t)72 << 20));
    unsigned char*  msk = (unsigned char*)(ws + ((size_t)88 << 20));

    k_conv<<<dim3(M + 4096), dim3(256), 0, stream>>>(x, Wq, Wk, Wv, Wo, xb, msk, Wt);
    k_gemm<0><<<dim3(M / 128, 3072 / 128), dim3(256), 0, stream>>>(
        xb, Wt, bq, bk, bv, Qb, Kb, Vtb, nullptr);
    k_attn<<<dim3(Bz * H * (S / 128)), dim3(256), 0, stream>>>(Qb, Kb, Vtb, msk, ctx);
    k_gemm<1><<<dim3(M / 128, 1024 / 128), dim3(256), 0, stream>>>(
        ctx, Wt + (size_t)3 * Dm * Dm, bo, nullptr, nullptr, nullptr, nullptr, nullptr, out);
}